// Round 4
// baseline (261.520 us; speedup 1.0000x reference)
//
#include <hip/hip_runtime.h>

#define NV 16384
#define BROWS 16          // L rows per block
#define JT 256            // j-tile width (floats); tile = 16 KB
#define NT (NV / JT)      // 64 tiles
#define THREADS 256
#define NBUF 4            // depth-3 prefetch

typedef const __attribute__((address_space(1))) void* as1_ptr;
typedef __attribute__((address_space(3))) void* as3_ptr;

__device__ __forceinline__ void gload_lds16(const float* g, float* l) {
  __builtin_amdgcn_global_load_lds((as1_ptr)g, (as3_ptr)l, 16, 0, 0);
}

#define FENCE asm volatile("" ::: "memory")
#define WAITV(n) asm volatile("s_waitcnt vmcnt(" #n ")" ::: "memory")

__global__ __launch_bounds__(THREADS, 2) void lap_loss_kernel(
    const float* __restrict__ x, const float* __restrict__ L,
    float* __restrict__ out) {
  __shared__ float lbuf[NBUF][BROWS * JT];  // 4 x 16 KB

  const int lane = threadIdx.x & 63;
  const int w    = threadIdx.x >> 6;     // wave id == batch index b
  const size_t i0 = (size_t)blockIdx.x * BROWS;

  // wave w stages rows i0+4w .. i0+4w+3; lane covers 16B of each row
  const float* gL[4];
#pragma unroll
  for (int r = 0; r < 4; ++r)
    gL[r] = L + (i0 + 4 * w + r) * NV + lane * 4;

  // wave w's x stream: x[w][j][d], lane owns j-quad 4*lane (48B)
  const float* gx = x + (size_t)w * NV * 3 + lane * 12;

  float acc[BROWS][3];
#pragma unroll
  for (int r = 0; r < BROWS; ++r)
#pragma unroll
    for (int d = 0; d < 3; ++d) acc[r][d] = 0.f;

  // ---- prologue: x(0), then gl_lds for tiles 0,1,2 ----
  float4 xc0 = *(const float4*)(gx + 0);
  float4 xc1 = *(const float4*)(gx + 4);
  float4 xc2 = *(const float4*)(gx + 8);
  FENCE;
#pragma unroll
  for (int tp = 0; tp < 3; ++tp)
#pragma unroll
    for (int r = 0; r < 4; ++r)
      gload_lds16(gL[r] + (size_t)tp * JT, &lbuf[tp][(4 * w + r) * JT]);

#pragma unroll 1
  for (int t = 0; t < NT; ++t) {
    const int cur = t & (NBUF - 1);

    // 1) x(t+1) prefetch into regs (issued FIRST, so its implicit use-wait
    //    next iteration keeps the L prefetches behind it in flight)
    float4 xn0, xn1, xn2;
    if (t + 1 < NT) {
      const float* gxn = gx + (size_t)(t + 1) * JT * 3;
      xn0 = *(const float4*)(gxn + 0);
      xn1 = *(const float4*)(gxn + 4);
      xn2 = *(const float4*)(gxn + 8);
    }
    FENCE;

    // 2) gl_lds prefetch L(t+3) into buf[(t+3)%4] (= buf[(t-1)%4], whose
    //    readers finished at tile t-1's closing barrier)
    if (t + 3 < NT) {
#pragma unroll
      for (int r = 0; r < 4; ++r)
        gload_lds16(gL[r] + (size_t)(t + 3) * JT,
                    &lbuf[(t + 3) & (NBUF - 1)][(4 * w + r) * JT]);
    }

    // 3) counted wait: force this wave's L(t) gl_lds complete, keep the
    //    newer prefetches (L(t+1..t+3) + x) in flight. Exact per-t counts.
    if (t == 0)            WAITV(15);
    else if (t == 1)       WAITV(18);
    else if (t <= NT - 4)  WAITV(21);
    else if (t == NT - 3)  WAITV(17);
    else if (t == NT - 2)  WAITV(13);
    else                   WAITV(0);
    __builtin_amdgcn_s_barrier();
    FENCE;

    // 4) compute tile t: 16 rows x 12 FMAs per lane-j
    {
      const float xf[12] = {xc0.x, xc0.y, xc0.z, xc0.w,
                            xc1.x, xc1.y, xc1.z, xc1.w,
                            xc2.x, xc2.y, xc2.z, xc2.w};
#pragma unroll
      for (int r = 0; r < BROWS; ++r) {
        float4 lv = *(const float4*)&lbuf[cur][r * JT + lane * 4];
        const float lf[4] = {lv.x, lv.y, lv.z, lv.w};
#pragma unroll
        for (int jj = 0; jj < 4; ++jj)
#pragma unroll
          for (int d = 0; d < 3; ++d)
            acc[r][d] = fmaf(lf[jj], xf[jj * 3 + d], acc[r][d]);
      }
    }

    FENCE;
    __builtin_amdgcn_s_barrier();  // all waves done reading lbuf[cur]
    FENCE;

    xc0 = xn0; xc1 = xn1; xc2 = xn2;
  }

  // ---- butterfly-reduce each (row,d) partial over 64 lanes, square ----
  float s = 0.f;
#pragma unroll
  for (int r = 0; r < BROWS; ++r)
#pragma unroll
    for (int d = 0; d < 3; ++d) {
      float v = acc[r][d];
#pragma unroll
      for (int off = 32; off > 0; off >>= 1)
        v += __shfl_xor(v, off, 64);
      s += v * v;
    }

  if (lane == 0) atomicAdd(&out[w], s);  // wave w owns batch w

}

extern "C" void kernel_launch(void* const* d_in, const int* in_sizes, int n_in,
                              void* d_out, int out_size, void* d_ws, size_t ws_size,
                              hipStream_t stream) {
  const float* x = (const float*)d_in[0];
  const float* L = (const float*)d_in[1];
  float* out = (float*)d_out;

  // Harness poisons d_out with 0xAA and never re-poisons between replays.
  hipMemsetAsync(out, 0, out_size * sizeof(float), stream);

  const int nblocks = NV / BROWS;  // 1024 blocks; 2/CU resident, 2 exact rounds
  lap_loss_kernel<<<nblocks, THREADS, 0, stream>>>(x, L, out);
}